// Round 12
// baseline (250.708 us; speedup 1.0000x reference)
//
#include <hip/hip_runtime.h>

#define EPS 1e-3f

// ---------------- workspace layout (float slots) ----------------
// bytes 0..28671 : bf16 fused weights in FRAG-MAJOR x32 layout (init_k blk 0)
//   w1frag  u16[4 frag][64 lane][8]   @ u16 0     (4KB)
//   w2afrag u16[8 frag][64 lane][8]   @ u16 2048  (8KB)
//   w2bfrag u16[16 frag][64 lane][8]  @ u16 6144  (16KB)  frag = mt*4+ks
#define OFF_T2B    7168              // f32[64]
#define OFF_MPP    7232              // f32[64][64] max-pool partials (memset)
#define OFF_MPF    11328             // f32[64]     final max-pool (fin_k)
#define OFF_CNT    11392             // i32[20016]  histogram (memset w/ mpp)
#define OFF_OFFS   31408             // i32[S+1] CSR offsets
#define OFF_CUR    51424             // i32[S]   scatter cursors
#define OFF_INPS   71424             // bf16[N][16] sorted inputs (32B/pt)

typedef short short8 __attribute__((ext_vector_type(8)));
typedef float f32x4 __attribute__((ext_vector_type(4)));

union U4 { unsigned u[4]; short8 s8; uint4 u4; };

__device__ inline unsigned short f2bf(float f) {           // RNE f32->bf16
    unsigned u = __float_as_uint(f);
    return (unsigned short)((u + 0x7FFFu + ((u >> 16) & 1u)) >> 16);
}

// block 0: fuse BN into bf16 weights; blocks 1..: histogram of unq
__global__ __launch_bounds__(256) void init_k(
    const float* __restrict__ W1,
    const float* __restrict__ g1, const float* __restrict__ b1,
    const float* __restrict__ m1, const float* __restrict__ v1,
    const float* __restrict__ W2a,
    const float* __restrict__ g2a, const float* __restrict__ b2a,
    const float* __restrict__ m2a, const float* __restrict__ v2a,
    const float* __restrict__ W2b,
    const float* __restrict__ g2b, const float* __restrict__ b2b,
    const float* __restrict__ m2b, const float* __restrict__ v2b,
    unsigned short* __restrict__ wsu, float* __restrict__ wsf,
    const int* __restrict__ unq, int* __restrict__ cnt, int N)
{
    const int t = threadIdx.x;
    if (blockIdx.x == 0) {
        for (int i = t; i < 2048; i += 256) {           // w1frag
            int mt = i >> 9, lane = (i >> 3) & 63, j = i & 7;
            int c = lane & 15, g = lane >> 4;
            int k = g * 8 + j, ch = mt * 16 + c;
            float s = g1[ch] * rsqrtf(v1[ch] + EPS);
            float val = (k < 16) ? W1[k * 64 + ch] * s
                      : (k == 16 ? b1[ch] - m1[ch] * s : 0.f);
            wsu[i] = f2bf(val);
        }
        for (int i = t; i < 4096; i += 256) {           // w2afrag
            int mt = i >> 9, lane = (i >> 3) & 63, j = i & 7;
            int c = lane & 15, g = lane >> 4;
            int k = g * 8 + j, ch = mt * 16 + c;
            float s = g2a[ch] * rsqrtf(v2a[ch] + EPS);
            float val = (k < 16) ? W2a[k * 128 + ch] * s
                      : (k == 16 ? b2a[ch] - m2a[ch] * s : 0.f);
            wsu[2048 + i] = f2bf(val);
        }
        for (int i = t; i < 8192; i += 256) {           // w2bfrag (frag=mt*4+ks)
            int f = i >> 9, lane = (i >> 3) & 63, j = i & 7;
            int mt = f >> 2, ks = f & 3;
            int c = lane & 15, g = lane >> 4;
            int k = ks * 32 + g * 8 + j, ch = mt * 16 + c;
            float s = g2b[ch] * rsqrtf(v2b[ch] + EPS);
            wsu[6144 + i] = f2bf(W2b[k * 64 + ch] * s);
        }
        if (t < 64) {
            float s = g2b[t] * rsqrtf(v2b[t] + EPS);
            wsf[OFF_T2B + t] = b2b[t] - m2b[t] * s;
        }
    } else {
        const int i = (blockIdx.x - 1) * 256 + t;
        if (i < N) atomicAdd(&cnt[unq[i]], 1);
    }
}

// serial-per-thread two-pass scan
__global__ __launch_bounds__(1024) void scan_k(
    const int* __restrict__ cnt, int* __restrict__ offs,
    int* __restrict__ cur, int S)
{
    __shared__ int tot[1024];
    const int t = threadIdx.x;
    const int E = (S + 1023) >> 10;
    const int i0 = t * E;
    int run = 0;
    for (int j = 0; j < E; ++j) {
        const int i = i0 + j;
        run += (i < S) ? cnt[i] : 0;
    }
    tot[t] = run;
    __syncthreads();
    for (int d = 1; d < 1024; d <<= 1) {
        int x = (t >= d) ? tot[t - d] : 0;
        __syncthreads();
        tot[t] += x;
        __syncthreads();
    }
    int base = (t == 0) ? 0 : tot[t - 1];
    for (int j = 0; j < E; ++j) {
        const int i = i0 + j;
        if (i < S) {
            offs[i] = base;
            cur[i]  = base;
            base += cnt[i];
        }
    }
    if (t == 1023) offs[S] = tot[1023];
}

// one 16-pt tile of branch 2: phase B (h, reg w2a) -> scr -> phase C (LDS w2b)
__device__ __forceinline__ void b2_tile(
    const U4& bf, bool act, const short8 (&w2a)[8],
    const char* __restrict__ w2bs, char* __restrict__ scr,
    float (&mp)[16], int lane, int c, int g)
{
    const f32x4 zero4 = {0.f, 0.f, 0.f, 0.f};
    __builtin_amdgcn_wave_barrier();            // scr reuse fence (prev tile read)
    #pragma unroll
    for (int mt = 0; mt < 8; ++mt) {
        f32x4 hT = __builtin_amdgcn_mfma_f32_16x16x32_bf16(w2a[mt], bf.s8, zero4, 0, 0, 0);
        float h0 = fmaxf(hT[0], 0.f), h1 = fmaxf(hT[1], 0.f);
        float h2 = fmaxf(hT[2], 0.f), h3 = fmaxf(hT[3], 0.f);
        unsigned lo, hi;
        asm("v_cvt_pk_bf16_f32 %0, %1, %2" : "=v"(lo) : "v"(h0), "v"(h1));
        asm("v_cvt_pk_bf16_f32 %0, %1, %2" : "=v"(hi) : "v"(h2), "v"(h3));
        const int gw = 2 * (mt & 1) + (g >> 1);
        *reinterpret_cast<uint2*>(
            &scr[(mt >> 1) * 1024 + (gw * 16 + c) * 16 + (g & 1) * 8])
            = make_uint2(lo, hi);
    }
    __builtin_amdgcn_wave_barrier();
    f32x4 y2t[4];
    #pragma unroll
    for (int mt = 0; mt < 4; ++mt) y2t[mt] = zero4;
    #pragma unroll
    for (int ks = 0; ks < 4; ++ks) {
        short8 hb = *reinterpret_cast<const short8*>(&scr[ks * 1024 + lane * 16]);
        #pragma unroll
        for (int mt = 0; mt < 4; ++mt) {
            short8 a = *reinterpret_cast<const short8*>(
                &w2bs[((mt * 4 + ks) * 64 + lane) * 16]);
            y2t[mt] = __builtin_amdgcn_mfma_f32_16x16x32_bf16(a, hb, y2t[mt], 0, 0, 0);
        }
    }
    #pragma unroll
    for (int mt = 0; mt < 4; ++mt) {
        #pragma unroll
        for (int r = 0; r < 4; ++r)
            mp[mt * 4 + r] = act ? fmaxf(mp[mt * 4 + r], y2t[mt][r]) : mp[mt * 4 + r];
    }
}

// Branch-2 + global max-pool. Lean per-wave state (w2a: 32 VGPR; w2b: LDS
// frag-major conflict-free; scr: single-buffer conflict-free). No atomics
// in the chunk loop. Full chunks take a mask-free prefetched fast path.
__global__ __launch_bounds__(256, 4) void br2_k(
    const float* __restrict__ inputs,
    const uint4* __restrict__ wsw,
    const float* __restrict__ wsf,
    float* __restrict__ mpp,
    int N)
{
    __shared__ __align__(16) char w2bs[16384];      // [16 frag][64 lane][16B]
    __shared__ __align__(16) char scrs[4][4096];    // per-wave h staging
    __shared__ float mpb[64];

    const int tid  = threadIdx.x;
    const int wv   = tid >> 6;
    const int lane = tid & 63;
    const int c = lane & 15;
    const int g = lane >> 4;

    #pragma unroll
    for (int u = 0; u < 4; ++u)                     // w2b -> LDS (1024 uint4)
        reinterpret_cast<uint4*>(w2bs)[u * 256 + tid] = wsw[768 + u * 256 + tid];
    if (tid < 64) mpb[tid] = 0.f;
    __syncthreads();

    short8 w2a[8];                                   // 32 VGPR
    #pragma unroll
    for (int s = 0; s < 8; ++s) {
        U4 t; t.u4 = wsw[256 + s * 64 + lane]; w2a[s] = t.s8;
    }
    #pragma unroll
    for (int s = 0; s < 8; ++s) asm volatile("" : "+v"(w2a[s]));

    char* scr = scrs[wv];
    float mp[16];
    #pragma unroll
    for (int j = 0; j < 16; ++j) mp[j] = -3.0e38f;   // bias deferred

    const long stride = (long)gridDim.x * 256;
    for (long base = (long)blockIdx.x * 256 + (long)wv * 64; base < N; base += stride) {
        const long nrem = (long)N - base;
        if (nrem >= 64) {
            // ---- fast path: prefetch all 8 input vectors, no masks ----
            float4 f0[4], f1[4];
            if (g < 2) {
                const float* ip = inputs + (base + c) * 16 + g * 8;
                #pragma unroll
                for (int ti = 0; ti < 4; ++ti) {
                    const float4* p = reinterpret_cast<const float4*>(ip + ti * 256);
                    f0[ti] = p[0]; f1[ti] = p[1];
                }
            }
            #pragma unroll
            for (int ti = 0; ti < 4; ++ti) {
                U4 bf;
                if (g < 2) {
                    asm("v_cvt_pk_bf16_f32 %0, %1, %2" : "=v"(bf.u[0]) : "v"(f0[ti].x), "v"(f0[ti].y));
                    asm("v_cvt_pk_bf16_f32 %0, %1, %2" : "=v"(bf.u[1]) : "v"(f0[ti].z), "v"(f0[ti].w));
                    asm("v_cvt_pk_bf16_f32 %0, %1, %2" : "=v"(bf.u[2]) : "v"(f1[ti].x), "v"(f1[ti].y));
                    asm("v_cvt_pk_bf16_f32 %0, %1, %2" : "=v"(bf.u[3]) : "v"(f1[ti].z), "v"(f1[ti].w));
                } else {
                    bf.u[0] = (g == 2) ? 0x00003F80u : 0u;   // k16 = 1.0 (bias)
                    bf.u[1] = 0u; bf.u[2] = 0u; bf.u[3] = 0u;
                }
                b2_tile(bf, true, w2a, w2bs, scr, mp, lane, c, g);
            }
        } else {
            // ---- tail path: per-tile masked ----
            #pragma unroll
            for (int ti = 0; ti < 4; ++ti) {
                if ((long)ti * 16 >= nrem) break;
                const bool act = (long)(ti * 16 + c) < nrem;
                U4 bf;
                if (g < 2) {
                    const long row = act ? (base + ti * 16 + c) : (long)(N - 1);
                    const float4* p = reinterpret_cast<const float4*>(inputs + row * 16 + g * 8);
                    float4 q0 = p[0], q1 = p[1];
                    asm("v_cvt_pk_bf16_f32 %0, %1, %2" : "=v"(bf.u[0]) : "v"(q0.x), "v"(q0.y));
                    asm("v_cvt_pk_bf16_f32 %0, %1, %2" : "=v"(bf.u[1]) : "v"(q0.z), "v"(q0.w));
                    asm("v_cvt_pk_bf16_f32 %0, %1, %2" : "=v"(bf.u[2]) : "v"(q1.x), "v"(q1.y));
                    asm("v_cvt_pk_bf16_f32 %0, %1, %2" : "=v"(bf.u[3]) : "v"(q1.z), "v"(q1.w));
                    if (!act) { bf.u[0] = 0u; bf.u[1] = 0u; bf.u[2] = 0u; bf.u[3] = 0u; }
                } else {
                    bf.u[0] = (g == 2 && act) ? 0x00003F80u : 0u;
                    bf.u[1] = 0u; bf.u[2] = 0u; bf.u[3] = 0u;
                }
                b2_tile(bf, act, w2a, w2bs, scr, mp, lane, c, g);
            }
        }
    }

    // ---- reduce raw max over the 16 column-lanes ----
    #pragma unroll
    for (int j = 0; j < 16; ++j) {
        float x = mp[j];
        x = fmaxf(x, __shfl_xor(x, 1, 64));
        x = fmaxf(x, __shfl_xor(x, 2, 64));
        x = fmaxf(x, __shfl_xor(x, 4, 64));
        x = fmaxf(x, __shfl_xor(x, 8, 64));
        mp[j] = x;
    }
    if (c == 0) {   // deferred bias + relu, block-level LDS max
        #pragma unroll
        for (int mt = 0; mt < 4; ++mt)
            #pragma unroll
            for (int r = 0; r < 4; ++r) {
                const int ch = mt * 16 + g * 4 + r;
                const float v = fmaxf(mp[mt * 4 + r] + wsf[OFF_T2B + ch], 0.f);
                atomicMax(reinterpret_cast<int*>(&mpb[ch]), __float_as_int(v));
            }
    }
    __syncthreads();
    if (tid < 64)
        atomicMax(reinterpret_cast<int*>(mpp + (blockIdx.x & 63) * 64 + tid),
                  __float_as_int(mpb[tid]));
}

// pure scatter: thread i -> point i; cursor atomic + 32B bf16 row write
__global__ __launch_bounds__(256) void scat_k(
    const float* __restrict__ inputs,
    const int*   __restrict__ unq,
    int*         __restrict__ cur,
    uint4*       __restrict__ inpS,
    int N)
{
    const int i = blockIdx.x * 256 + threadIdx.x;
    if (i >= N) return;
    const int seg = unq[i];
    const int pos = atomicAdd(&cur[seg], 1);

    const float4* p = reinterpret_cast<const float4*>(inputs + (size_t)i * 16);
    float4 a0 = p[0], a1 = p[1], a2 = p[2], a3 = p[3];
    unsigned pk[8];
    asm("v_cvt_pk_bf16_f32 %0, %1, %2" : "=v"(pk[0]) : "v"(a0.x), "v"(a0.y));
    asm("v_cvt_pk_bf16_f32 %0, %1, %2" : "=v"(pk[1]) : "v"(a0.z), "v"(a0.w));
    asm("v_cvt_pk_bf16_f32 %0, %1, %2" : "=v"(pk[2]) : "v"(a1.x), "v"(a1.y));
    asm("v_cvt_pk_bf16_f32 %0, %1, %2" : "=v"(pk[3]) : "v"(a1.z), "v"(a1.w));
    asm("v_cvt_pk_bf16_f32 %0, %1, %2" : "=v"(pk[4]) : "v"(a2.x), "v"(a2.y));
    asm("v_cvt_pk_bf16_f32 %0, %1, %2" : "=v"(pk[5]) : "v"(a2.z), "v"(a2.w));
    asm("v_cvt_pk_bf16_f32 %0, %1, %2" : "=v"(pk[6]) : "v"(a3.x), "v"(a3.y));
    asm("v_cvt_pk_bf16_f32 %0, %1, %2" : "=v"(pk[7]) : "v"(a3.z), "v"(a3.w));

    inpS[(size_t)pos * 2]     = make_uint4(pk[0], pk[1], pk[2], pk[3]);
    inpS[(size_t)pos * 2 + 1] = make_uint4(pk[4], pk[5], pk[6], pk[7]);
}

// finalize global max-pool: 64 slots -> 64 channels
__global__ __launch_bounds__(64) void fin_k(
    const float* __restrict__ mpp, float* __restrict__ mpf)
{
    const int t = threadIdx.x;
    float m = 0.f;
    #pragma unroll
    for (int s = 0; s < 64; ++s)
        m = fmaxf(m, mpp[s * 64 + t]);
    mpf[t] = m;
}

// One wave per segment on SORTED bf16 inputs, grid-stride over segments.
__global__ __launch_bounds__(256, 4) void seg1_k(
    const uint4* __restrict__ inpS,
    const int*   __restrict__ offs,
    const uint4* __restrict__ wsw,
    const float* __restrict__ mpf,
    float* __restrict__ out,
    int S)
{
    __shared__ float scr3[4][192];

    const int tid  = threadIdx.x;
    const int wv   = tid >> 6;
    const int lane = tid & 63;
    const int c = lane & 15;
    const int g = lane >> 4;

    short8 w1[4];                                 // 16 VGPRs, from global (L2-hot)
    #pragma unroll
    for (int mt = 0; mt < 4; ++mt) {
        U4 t; t.u4 = wsw[mt * 64 + lane]; w1[mt] = t.s8;
    }
    const float mpl = mpf[lane];
    float* sr = scr3[wv];
    const f32x4 zero4 = {0.f, 0.f, 0.f, 0.f};

    const int nw = gridDim.x * 4;
    for (int seg = blockIdx.x * 4 + wv; seg < S; seg += nw) {
        const int su    = __builtin_amdgcn_readfirstlane(seg);
        const int start = offs[su];
        const int end   = offs[su + 1];

        f32x4 as[4], am[4];
        #pragma unroll
        for (int mt = 0; mt < 4; ++mt) { as[mt] = zero4; am[mt] = zero4; }

        for (int base = start; base < end; base += 64) {
            const int nrem = end - base;
            #pragma unroll
            for (int ti = 0; ti < 4; ++ti) {
                if (ti * 16 >= nrem) break;                 // wave-uniform
                const bool act = (ti * 16 + c) < nrem;

                U4 bf;
                if (g < 2) {
                    const int row = min(base + ti * 16 + c, end - 1);
                    uint4 q = inpS[(size_t)row * 2 + g];
                    bf.u[0] = act ? q.x : 0u;
                    bf.u[1] = act ? q.y : 0u;
                    bf.u[2] = act ? q.z : 0u;
                    bf.u[3] = act ? q.w : 0u;
                } else {
                    bf.u[0] = (g == 2 && act) ? 0x00003F80u : 0u;
                    bf.u[1] = 0u; bf.u[2] = 0u; bf.u[3] = 0u;
                }
                #pragma unroll
                for (int mt = 0; mt < 4; ++mt) {
                    f32x4 y1t = __builtin_amdgcn_mfma_f32_16x16x32_bf16(w1[mt], bf.s8, zero4, 0, 0, 0);
                    #pragma unroll
                    for (int r = 0; r < 4; ++r) {
                        float v = fmaxf(y1t[r], 0.f);   // inactive cols give 0
                        as[mt][r] += v;
                        am[mt][r]  = fmaxf(am[mt][r], v);
                    }
                }
            }
        }

        // ---- reduce across the 16 column-lanes ----
        #pragma unroll
        for (int mt = 0; mt < 4; ++mt) {
            #pragma unroll
            for (int r = 0; r < 4; ++r) {
                float xs = as[mt][r], xm = am[mt][r];
                xs += __shfl_xor(xs, 1, 64);  xm = fmaxf(xm, __shfl_xor(xm, 1, 64));
                xs += __shfl_xor(xs, 2, 64);  xm = fmaxf(xm, __shfl_xor(xm, 2, 64));
                xs += __shfl_xor(xs, 4, 64);  xm = fmaxf(xm, __shfl_xor(xm, 4, 64));
                xs += __shfl_xor(xs, 8, 64);  xm = fmaxf(xm, __shfl_xor(xm, 8, 64));
                as[mt][r] = xs; am[mt][r] = xm;
            }
        }

        // ---- stage channel-shuffled 192 floats, 3 coalesced line writes ----
        if (c == 0) {
            #pragma unroll
            for (int mt = 0; mt < 4; ++mt)
                #pragma unroll
                for (int r = 0; r < 4; ++r) {
                    const int ch = mt * 16 + g * 4 + r;
                    sr[ch * 3 + 0] = as[mt][r];
                    sr[ch * 3 + 1] = am[mt][r];
                }
        }
        sr[lane * 3 + 2] = mpl;
        __builtin_amdgcn_wave_barrier();
        asm volatile("s_waitcnt lgkmcnt(0)" ::: "memory");
        __builtin_amdgcn_sched_barrier(0);

        float* o = out + (size_t)seg * 192;
        #pragma unroll
        for (int p = 0; p < 3; ++p)
            o[p * 64 + lane] = sr[p * 64 + lane];
        __builtin_amdgcn_wave_barrier();
    }
}

extern "C" void kernel_launch(void* const* d_in, const int* in_sizes, int n_in,
                              void* d_out, int out_size, void* d_ws, size_t ws_size,
                              hipStream_t stream)
{
    const float* inputs = (const float*)d_in[0];
    const int*   unq    = (const int*)d_in[1];
    const float* W1  = (const float*)d_in[3];
    const float* g1  = (const float*)d_in[4];
    const float* b1  = (const float*)d_in[5];
    const float* m1  = (const float*)d_in[6];
    const float* v1  = (const float*)d_in[7];
    const float* W2a = (const float*)d_in[8];
    const float* g2a = (const float*)d_in[9];
    const float* b2a = (const float*)d_in[10];
    const float* m2a = (const float*)d_in[11];
    const float* v2a = (const float*)d_in[12];
    const float* W2b = (const float*)d_in[13];
    const float* g2b = (const float*)d_in[14];
    const float* b2b = (const float*)d_in[15];
    const float* m2b = (const float*)d_in[16];
    const float* v2b = (const float*)d_in[17];

    float* wsf = (float*)d_ws;
    float* out = (float*)d_out;
    const int N = in_sizes[0] / 16;
    const int S = out_size / 192;

    float* mpp  = wsf + OFF_MPP;
    float* mpf  = wsf + OFF_MPF;
    int*   cnt  = (int*)(wsf + OFF_CNT);
    int*   offs = (int*)(wsf + OFF_OFFS);
    int*   cur  = (int*)(wsf + OFF_CUR);
    uint4* inpS = (uint4*)(wsf + OFF_INPS);

    // zero mpp + mpf + cnt (contiguous region)
    hipMemsetAsync(mpp, 0, (size_t)(OFF_CNT + 20016 - OFF_MPP) * sizeof(float), stream);

    init_k<<<1 + (N + 255) / 256, 256, 0, stream>>>(
        W1, g1, b1, m1, v1, W2a, g2a, b2a, m2a, v2a, W2b, g2b, b2b, m2b, v2b,
        (unsigned short*)d_ws, wsf, unq, cnt, N);

    br2_k<<<2048, 256, 0, stream>>>(inputs, (const uint4*)d_ws, wsf, mpp, N);

    scan_k<<<1, 1024, 0, stream>>>(cnt, offs, cur, S);

    scat_k<<<(N + 255) / 256, 256, 0, stream>>>(inputs, unq, cur, inpS, N);

    fin_k<<<1, 64, 0, stream>>>(mpp, mpf);

    seg1_k<<<2048, 256, 0, stream>>>(inpS, offs, (const uint4*)d_ws,
                                     mpf, out, S);
}

// Round 13
// 213.365 us; speedup vs baseline: 1.1750x; 1.1750x over previous
//
#include <hip/hip_runtime.h>

#define EPS 1e-3f

// ---------------- workspace layout (float slots) ----------------
// bytes 0..28671 : bf16 fused weights in FRAG-MAJOR x32 layout (init_k blk 0)
//   w1frag  u16[4 frag][64 lane][8]   @ u16 0     (4KB)
//   w2afrag u16[8 frag][64 lane][8]   @ u16 2048  (8KB)
//   w2bfrag u16[16 frag][64 lane][8]  @ u16 6144  (16KB)  frag = mt*4+ks
#define OFF_T2B    7168              // f32[64]
#define OFF_MPP    7232              // f32[64][64] max-pool partials (memset)
#define OFF_CNT    11392             // i32[20016]  histogram (memset w/ mpp)
#define OFF_OFFS   31408             // i32[S+1] CSR offsets
#define OFF_CUR    51424             // i32[S]   scatter cursors
#define OFF_INPS   71424             // bf16[N][16] sorted inputs (32B/pt)

typedef short short8 __attribute__((ext_vector_type(8)));
typedef float f32x4 __attribute__((ext_vector_type(4)));

union U4 { unsigned u[4]; short8 s8; uint4 u4; };

__device__ inline unsigned short f2bf(float f) {           // RNE f32->bf16
    unsigned u = __float_as_uint(f);
    return (unsigned short)((u + 0x7FFFu + ((u >> 16) & 1u)) >> 16);
}

// block 0: fuse BN into bf16 weights; blocks 1..: histogram of unq
__global__ __launch_bounds__(256) void init_k(
    const float* __restrict__ W1,
    const float* __restrict__ g1, const float* __restrict__ b1,
    const float* __restrict__ m1, const float* __restrict__ v1,
    const float* __restrict__ W2a,
    const float* __restrict__ g2a, const float* __restrict__ b2a,
    const float* __restrict__ m2a, const float* __restrict__ v2a,
    const float* __restrict__ W2b,
    const float* __restrict__ g2b, const float* __restrict__ b2b,
    const float* __restrict__ m2b, const float* __restrict__ v2b,
    unsigned short* __restrict__ wsu, float* __restrict__ wsf,
    const int* __restrict__ unq, int* __restrict__ cnt, int N)
{
    const int t = threadIdx.x;
    if (blockIdx.x == 0) {
        for (int i = t; i < 2048; i += 256) {           // w1frag
            int mt = i >> 9, lane = (i >> 3) & 63, j = i & 7;
            int c = lane & 15, g = lane >> 4;
            int k = g * 8 + j, ch = mt * 16 + c;
            float s = g1[ch] * rsqrtf(v1[ch] + EPS);
            float val = (k < 16) ? W1[k * 64 + ch] * s
                      : (k == 16 ? b1[ch] - m1[ch] * s : 0.f);
            wsu[i] = f2bf(val);
        }
        for (int i = t; i < 4096; i += 256) {           // w2afrag
            int mt = i >> 9, lane = (i >> 3) & 63, j = i & 7;
            int c = lane & 15, g = lane >> 4;
            int k = g * 8 + j, ch = mt * 16 + c;
            float s = g2a[ch] * rsqrtf(v2a[ch] + EPS);
            float val = (k < 16) ? W2a[k * 128 + ch] * s
                      : (k == 16 ? b2a[ch] - m2a[ch] * s : 0.f);
            wsu[2048 + i] = f2bf(val);
        }
        for (int i = t; i < 8192; i += 256) {           // w2bfrag (frag=mt*4+ks)
            int f = i >> 9, lane = (i >> 3) & 63, j = i & 7;
            int mt = f >> 2, ks = f & 3;
            int c = lane & 15, g = lane >> 4;
            int k = ks * 32 + g * 8 + j, ch = mt * 16 + c;
            float s = g2b[ch] * rsqrtf(v2b[ch] + EPS);
            wsu[6144 + i] = f2bf(W2b[k * 64 + ch] * s);
        }
        if (t < 64) {
            float s = g2b[t] * rsqrtf(v2b[t] + EPS);
            wsf[OFF_T2B + t] = b2b[t] - m2b[t] * s;
        }
    } else {
        const int i = (blockIdx.x - 1) * 256 + t;
        if (i < N) atomicAdd(&cnt[unq[i]], 1);
    }
}

// serial-per-thread two-pass scan
__global__ __launch_bounds__(1024) void scan_k(
    const int* __restrict__ cnt, int* __restrict__ offs,
    int* __restrict__ cur, int S)
{
    __shared__ int tot[1024];
    const int t = threadIdx.x;
    const int E = (S + 1023) >> 10;
    const int i0 = t * E;
    int run = 0;
    for (int j = 0; j < E; ++j) {
        const int i = i0 + j;
        run += (i < S) ? cnt[i] : 0;
    }
    tot[t] = run;
    __syncthreads();
    for (int d = 1; d < 1024; d <<= 1) {
        int x = (t >= d) ? tot[t - d] : 0;
        __syncthreads();
        tot[t] += x;
        __syncthreads();
    }
    int base = (t == 0) ? 0 : tot[t - 1];
    for (int j = 0; j < E; ++j) {
        const int i = i0 + j;
        if (i < S) {
            offs[i] = base;
            cur[i]  = base;
            base += cnt[i];
        }
    }
    if (t == 1023) offs[S] = tot[1023];
}

// one 16-pt tile of branch 2: phase B (h, reg w2a) -> scr -> phase C (LDS w2b)
__device__ __forceinline__ void b2_tile(
    const U4& bf, bool act, const short8 (&w2a)[8],
    const char* __restrict__ w2bs, char* __restrict__ scr,
    float (&mp)[16], int lane, int c, int g)
{
    const f32x4 zero4 = {0.f, 0.f, 0.f, 0.f};
    __builtin_amdgcn_wave_barrier();            // scr reuse fence (prev tile read)
    #pragma unroll
    for (int mt = 0; mt < 8; ++mt) {
        f32x4 hT = __builtin_amdgcn_mfma_f32_16x16x32_bf16(w2a[mt], bf.s8, zero4, 0, 0, 0);
        float h0 = fmaxf(hT[0], 0.f), h1 = fmaxf(hT[1], 0.f);
        float h2 = fmaxf(hT[2], 0.f), h3 = fmaxf(hT[3], 0.f);
        unsigned lo, hi;
        asm("v_cvt_pk_bf16_f32 %0, %1, %2" : "=v"(lo) : "v"(h0), "v"(h1));
        asm("v_cvt_pk_bf16_f32 %0, %1, %2" : "=v"(hi) : "v"(h2), "v"(h3));
        const int gw = 2 * (mt & 1) + (g >> 1);
        *reinterpret_cast<uint2*>(
            &scr[(mt >> 1) * 1024 + (gw * 16 + c) * 16 + (g & 1) * 8])
            = make_uint2(lo, hi);
    }
    __builtin_amdgcn_wave_barrier();
    f32x4 y2t[4];
    #pragma unroll
    for (int mt = 0; mt < 4; ++mt) y2t[mt] = zero4;
    #pragma unroll
    for (int ks = 0; ks < 4; ++ks) {
        short8 hb = *reinterpret_cast<const short8*>(&scr[ks * 1024 + lane * 16]);
        #pragma unroll
        for (int mt = 0; mt < 4; ++mt) {
            short8 a = *reinterpret_cast<const short8*>(
                &w2bs[((mt * 4 + ks) * 64 + lane) * 16]);
            y2t[mt] = __builtin_amdgcn_mfma_f32_16x16x32_bf16(a, hb, y2t[mt], 0, 0, 0);
        }
    }
    #pragma unroll
    for (int mt = 0; mt < 4; ++mt) {
        #pragma unroll
        for (int r = 0; r < 4; ++r)
            mp[mt * 4 + r] = act ? fmaxf(mp[mt * 4 + r], y2t[mt][r]) : mp[mt * 4 + r];
    }
}

// Fused scatter + branch-2 + max-pool partials. Lean state: w2a 32 VGPR,
// w2b LDS frag-major, scr conflict-free. No prefetch arrays (no spill).
__global__ __launch_bounds__(256, 4) void brscat_k(
    const float* __restrict__ inputs,
    const int*   __restrict__ unq,
    int*         __restrict__ cur,
    uint4*       __restrict__ inpS,
    const uint4* __restrict__ wsw,
    const float* __restrict__ wsf,
    float* __restrict__ mpp,
    int N)
{
    __shared__ __align__(16) char w2bs[16384];      // [16 frag][64 lane][16B]
    __shared__ __align__(16) char scrs[4][4096];    // per-wave h staging
    __shared__ float mpb[64];

    const int tid  = threadIdx.x;
    const int wv   = tid >> 6;
    const int lane = tid & 63;
    const int c = lane & 15;
    const int g = lane >> 4;

    #pragma unroll
    for (int u = 0; u < 4; ++u)                     // w2b -> LDS (1024 uint4)
        reinterpret_cast<uint4*>(w2bs)[u * 256 + tid] = wsw[768 + u * 256 + tid];
    if (tid < 64) mpb[tid] = 0.f;
    __syncthreads();

    short8 w2a[8];                                   // 32 VGPR
    #pragma unroll
    for (int s = 0; s < 8; ++s) {
        U4 t; t.u4 = wsw[256 + s * 64 + lane]; w2a[s] = t.s8;
    }
    #pragma unroll
    for (int s = 0; s < 8; ++s) asm volatile("" : "+v"(w2a[s]));

    char* scr = scrs[wv];
    float mp[16];
    #pragma unroll
    for (int j = 0; j < 16; ++j) mp[j] = -3.0e38f;   // bias deferred

    const long stride = (long)gridDim.x * 256;
    for (long base = (long)blockIdx.x * 256 + (long)wv * 64; base < N; base += stride) {
        const long nrem = (long)N - base;

        // one scatter-cursor atomic per lane, issued at chunk top
        const long ip = base + lane;
        int pos = 0;
        if (ip < (long)N) pos = atomicAdd(&cur[unq[ip]], 1);

        #pragma unroll
        for (int ti = 0; ti < 4; ++ti) {
            if ((long)ti * 16 >= nrem) break;            // wave-uniform
            const bool act = (long)(ti * 16 + c) < nrem;

            // B-frag direct from global (lanes g<2), bias slot g=2
            U4 bf;
            if (g < 2) {
                const long row = act ? (base + ti * 16 + c) : (long)(N - 1);
                const float4* p = reinterpret_cast<const float4*>(inputs + row * 16 + g * 8);
                float4 q0 = p[0], q1 = p[1];
                asm("v_cvt_pk_bf16_f32 %0, %1, %2" : "=v"(bf.u[0]) : "v"(q0.x), "v"(q0.y));
                asm("v_cvt_pk_bf16_f32 %0, %1, %2" : "=v"(bf.u[1]) : "v"(q0.z), "v"(q0.w));
                asm("v_cvt_pk_bf16_f32 %0, %1, %2" : "=v"(bf.u[2]) : "v"(q1.x), "v"(q1.y));
                asm("v_cvt_pk_bf16_f32 %0, %1, %2" : "=v"(bf.u[3]) : "v"(q1.z), "v"(q1.w));
                if (!act) { bf.u[0] = 0u; bf.u[1] = 0u; bf.u[2] = 0u; bf.u[3] = 0u; }
            } else {
                bf.u[0] = (g == 2 && act) ? 0x00003F80u : 0u;   // k16 = 1.0 (bias)
                bf.u[1] = 0u; bf.u[2] = 0u; bf.u[3] = 0u;
            }

            // scatter this tile's 16 points (lane g holds half g of pt c)
            const int posc = __shfl(pos, ti * 16 + c, 64);
            if (g < 2 && act)
                inpS[(size_t)posc * 2 + g] = bf.u4;

            b2_tile(bf, act, w2a, w2bs, scr, mp, lane, c, g);
        }
    }

    // ---- reduce raw max over the 16 column-lanes ----
    #pragma unroll
    for (int j = 0; j < 16; ++j) {
        float x = mp[j];
        x = fmaxf(x, __shfl_xor(x, 1, 64));
        x = fmaxf(x, __shfl_xor(x, 2, 64));
        x = fmaxf(x, __shfl_xor(x, 4, 64));
        x = fmaxf(x, __shfl_xor(x, 8, 64));
        mp[j] = x;
    }
    if (c == 0) {   // deferred bias + relu, block-level LDS max
        #pragma unroll
        for (int mt = 0; mt < 4; ++mt)
            #pragma unroll
            for (int r = 0; r < 4; ++r) {
                const int ch = mt * 16 + g * 4 + r;
                const float v = fmaxf(mp[mt * 4 + r] + wsf[OFF_T2B + ch], 0.f);
                atomicMax(reinterpret_cast<int*>(&mpb[ch]), __float_as_int(v));
            }
    }
    __syncthreads();
    if (tid < 64)
        atomicMax(reinterpret_cast<int*>(mpp + (blockIdx.x & 63) * 64 + tid),
                  __float_as_int(mpb[tid]));
}

// One wave per segment on SORTED bf16 inputs, grid-stride. Max-pool
// finalization folded into the prologue (64 L2-hot loads per wave).
__global__ __launch_bounds__(256, 4) void seg1_k(
    const uint4* __restrict__ inpS,
    const int*   __restrict__ offs,
    const uint4* __restrict__ wsw,
    const float* __restrict__ mpp,
    float* __restrict__ out,
    int S)
{
    __shared__ float scr3[4][192];

    const int tid  = threadIdx.x;
    const int wv   = tid >> 6;
    const int lane = tid & 63;
    const int c = lane & 15;
    const int g = lane >> 4;

    short8 w1[4];                                 // 16 VGPRs, from global (L2-hot)
    #pragma unroll
    for (int mt = 0; mt < 4; ++mt) {
        U4 t; t.u4 = wsw[mt * 64 + lane]; w1[mt] = t.s8;
    }
    float mpl = 0.f;                               // finalize max-pool per wave
    #pragma unroll
    for (int s = 0; s < 64; ++s)
        mpl = fmaxf(mpl, mpp[s * 64 + lane]);

    float* sr = scr3[wv];
    const f32x4 zero4 = {0.f, 0.f, 0.f, 0.f};

    const int nw = gridDim.x * 4;
    for (int seg = blockIdx.x * 4 + wv; seg < S; seg += nw) {
        const int su    = __builtin_amdgcn_readfirstlane(seg);
        const int start = offs[su];
        const int end   = offs[su + 1];

        f32x4 as[4], am[4];
        #pragma unroll
        for (int mt = 0; mt < 4; ++mt) { as[mt] = zero4; am[mt] = zero4; }

        for (int base = start; base < end; base += 64) {
            const int nrem = end - base;
            #pragma unroll
            for (int ti = 0; ti < 4; ++ti) {
                if (ti * 16 >= nrem) break;                 // wave-uniform
                const bool act = (ti * 16 + c) < nrem;

                U4 bf;
                if (g < 2) {
                    const int row = min(base + ti * 16 + c, end - 1);
                    uint4 q = inpS[(size_t)row * 2 + g];
                    bf.u[0] = act ? q.x : 0u;
                    bf.u[1] = act ? q.y : 0u;
                    bf.u[2] = act ? q.z : 0u;
                    bf.u[3] = act ? q.w : 0u;
                } else {
                    bf.u[0] = (g == 2 && act) ? 0x00003F80u : 0u;
                    bf.u[1] = 0u; bf.u[2] = 0u; bf.u[3] = 0u;
                }
                #pragma unroll
                for (int mt = 0; mt < 4; ++mt) {
                    f32x4 y1t = __builtin_amdgcn_mfma_f32_16x16x32_bf16(w1[mt], bf.s8, zero4, 0, 0, 0);
                    #pragma unroll
                    for (int r = 0; r < 4; ++r) {
                        float v = fmaxf(y1t[r], 0.f);   // inactive cols give 0
                        as[mt][r] += v;
                        am[mt][r]  = fmaxf(am[mt][r], v);
                    }
                }
            }
        }

        // ---- reduce across the 16 column-lanes ----
        #pragma unroll
        for (int mt = 0; mt < 4; ++mt) {
            #pragma unroll
            for (int r = 0; r < 4; ++r) {
                float xs = as[mt][r], xm = am[mt][r];
                xs += __shfl_xor(xs, 1, 64);  xm = fmaxf(xm, __shfl_xor(xm, 1, 64));
                xs += __shfl_xor(xs, 2, 64);  xm = fmaxf(xm, __shfl_xor(xm, 2, 64));
                xs += __shfl_xor(xs, 4, 64);  xm = fmaxf(xm, __shfl_xor(xm, 4, 64));
                xs += __shfl_xor(xs, 8, 64);  xm = fmaxf(xm, __shfl_xor(xm, 8, 64));
                as[mt][r] = xs; am[mt][r] = xm;
            }
        }

        // ---- stage channel-shuffled 192 floats, 3 coalesced line writes ----
        if (c == 0) {
            #pragma unroll
            for (int mt = 0; mt < 4; ++mt)
                #pragma unroll
                for (int r = 0; r < 4; ++r) {
                    const int ch = mt * 16 + g * 4 + r;
                    sr[ch * 3 + 0] = as[mt][r];
                    sr[ch * 3 + 1] = am[mt][r];
                }
        }
        sr[lane * 3 + 2] = mpl;
        __builtin_amdgcn_wave_barrier();
        asm volatile("s_waitcnt lgkmcnt(0)" ::: "memory");
        __builtin_amdgcn_sched_barrier(0);

        float* o = out + (size_t)seg * 192;
        #pragma unroll
        for (int p = 0; p < 3; ++p)
            o[p * 64 + lane] = sr[p * 64 + lane];
        __builtin_amdgcn_wave_barrier();
    }
}

extern "C" void kernel_launch(void* const* d_in, const int* in_sizes, int n_in,
                              void* d_out, int out_size, void* d_ws, size_t ws_size,
                              hipStream_t stream)
{
    const float* inputs = (const float*)d_in[0];
    const int*   unq    = (const int*)d_in[1];
    const float* W1  = (const float*)d_in[3];
    const float* g1  = (const float*)d_in[4];
    const float* b1  = (const float*)d_in[5];
    const float* m1  = (const float*)d_in[6];
    const float* v1  = (const float*)d_in[7];
    const float* W2a = (const float*)d_in[8];
    const float* g2a = (const float*)d_in[9];
    const float* b2a = (const float*)d_in[10];
    const float* m2a = (const float*)d_in[11];
    const float* v2a = (const float*)d_in[12];
    const float* W2b = (const float*)d_in[13];
    const float* g2b = (const float*)d_in[14];
    const float* b2b = (const float*)d_in[15];
    const float* m2b = (const float*)d_in[16];
    const float* v2b = (const float*)d_in[17];

    float* wsf = (float*)d_ws;
    float* out = (float*)d_out;
    const int N = in_sizes[0] / 16;
    const int S = out_size / 192;

    float* mpp  = wsf + OFF_MPP;
    int*   cnt  = (int*)(wsf + OFF_CNT);
    int*   offs = (int*)(wsf + OFF_OFFS);
    int*   cur  = (int*)(wsf + OFF_CUR);
    uint4* inpS = (uint4*)(wsf + OFF_INPS);

    // zero mpp + cnt (contiguous region)
    hipMemsetAsync(mpp, 0, (size_t)(OFF_CNT + 20016 - OFF_MPP) * sizeof(float), stream);

    init_k<<<1 + (N + 255) / 256, 256, 0, stream>>>(
        W1, g1, b1, m1, v1, W2a, g2a, b2a, m2a, v2a, W2b, g2b, b2b, m2b, v2b,
        (unsigned short*)d_ws, wsf, unq, cnt, N);

    scan_k<<<1, 1024, 0, stream>>>(cnt, offs, cur, S);

    brscat_k<<<1024, 256, 0, stream>>>(inputs, unq, cur, inpS,
                                       (const uint4*)d_ws, wsf, mpp, N);

    seg1_k<<<1024, 256, 0, stream>>>(inpS, offs, (const uint4*)d_ws,
                                     mpp, out, S);
}